// Round 9
// baseline (161.496 us; speedup 1.0000x reference)
//
#include <hip/hip_runtime.h>
#include <hip/hip_bf16.h>

#define BB 8
#define CC 128
#define NN 4096
#define KCQ 32

typedef unsigned short u16;
typedef unsigned int u32;
typedef unsigned char u8;
typedef __bf16 bf16x8 __attribute__((ext_vector_type(8)));
typedef float f32x4 __attribute__((ext_vector_type(4)));
typedef long i64;

__device__ __forceinline__ u16 f2bf(float f){
  u32 u = __builtin_bit_cast(u32, f);
  u32 r = u + 0x7FFFu + ((u >> 16) & 1u);
  return (u16)(r >> 16);
}
__device__ __forceinline__ u32 cvtpk(float lo, float hi){
  u32 r; asm("v_cvt_pk_bf16_f32 %0, %1, %2" : "=v"(r) : "v"(lo), "v"(hi)); return r;
}
__device__ __forceinline__ u32 pk_fp8x4(float a, float b, float c, float d){
  int v = 0;
  v = __builtin_amdgcn_cvt_pk_fp8_f32(a, b, v, false);
  v = __builtin_amdgcn_cvt_pk_fp8_f32(c, d, v, true);
  return (u32)v;
}

// ---- kernel 0: weights f32 -> bf16 (Wq folds 1/sqrt(32)*log2(e) for exp2 softmax)
__global__ __launch_bounds__(256) void k_prep_w(const float* Wq, const float* Wk,
                                                const float* Wv, const float* Wo,
                                                u16* wsq, u16* wsk, u16* wsv, u16* wso){
  int i = blockIdx.x * 256 + threadIdx.x;
  const float SC = 0.2550350f; // log2(e)/sqrt(32)
  if (i < 4096)       wsq[i]        = f2bf(Wq[i] * SC);
  else if (i < 8192)  wsk[i-4096]   = f2bf(Wk[i-4096]);
  else if (i < 24576) wsv[i-8192]   = f2bf(Wv[i-8192]);
  else if (i < 40960) wso[i-24576]  = f2bf(Wo[i-24576]);
}

// ---- kernel 1: fused transpose+projection. 512 blocks x 512 thr.
// Wave pair per n-slice: even {Q0,Q1,K0,K1,V0,V1}, odd {V2..V7}. V fp8 via LDS
// transpose, 64B-coalesced writeout.
__global__ __launch_bounds__(512) void k_projx(const float* x, const u16* wq, const u16* wk,
                                               const u16* wv, u16* Qm, u16* Km, u8* Vt8){
  __shared__ __align__(16) u16 xL[64*132];
  int b = blockIdx.x >> 6, nb = (blockIdx.x & 63) * 64;
  int t = threadIdx.x;
  int n = t & 63, cg = t >> 6;
  #pragma unroll
  for (int it = 0; it < 16; ++it){
    int c = it*8 + cg;
    xL[n*132 + c] = f2bf(x[((size_t)b*CC + c)*NN + nb + n]);
  }
  __syncthreads();
  int w = t >> 6, l = t & 63, a = l & 15, g = l >> 4;
  int ns = w >> 1, half = w & 1;
  int n0 = nb + ns*16;
  bf16x8 xa[4];
  #pragma unroll
  for (int kc = 0; kc < 4; ++kc)
    xa[kc] = *(const bf16x8*)(xL + (ns*16 + a)*132 + kc*32 + g*8);
  __syncthreads();

  u32* vbuf = (u32*)xL;                  // [128 vchan][16 dwords], chunk ^ ((row>>1)&3)
  auto Vjob = [&](int vt){
    f32x4 acc = {0.f,0.f,0.f,0.f};
    #pragma unroll
    for (int kc = 0; kc < 4; ++kc){
      bf16x8 wa = ((const bf16x8*)(wv + (size_t)(vt*16 + a) * CC))[kc*4 + g];
      acc = __builtin_amdgcn_mfma_f32_16x16x32_bf16(xa[kc], wa, acc, 0,0,0);
    }
    int row = vt*16 + a;
    vbuf[row*16 + ((ns ^ ((a>>1)&3)) << 2) + g] = pk_fp8x4(acc[0], acc[1], acc[2], acc[3]);
  };

  if (half == 0){
    #pragma unroll
    for (int qt = 0; qt < 2; ++qt){
      f32x4 accq = {0.f,0.f,0.f,0.f}, acck = {0.f,0.f,0.f,0.f};
      #pragma unroll
      for (int kc = 0; kc < 4; ++kc){
        bf16x8 wbq = ((const bf16x8*)(wq + (size_t)(qt*16 + a) * CC))[kc*4 + g];
        bf16x8 wbk = ((const bf16x8*)(wk + (size_t)(qt*16 + a) * CC))[kc*4 + g];
        accq = __builtin_amdgcn_mfma_f32_16x16x32_bf16(xa[kc], wbq, accq, 0,0,0);
        acck = __builtin_amdgcn_mfma_f32_16x16x32_bf16(xa[kc], wbk, acck, 0,0,0);
      }
      #pragma unroll
      for (int r = 0; r < 4; ++r){
        Qm[((size_t)b*NN + n0 + 4*g + r) * KCQ + qt*16 + a] = f2bf(accq[r]);
        Km[((size_t)b*NN + n0 + 4*g + r) * KCQ + qt*16 + a] = f2bf(acck[r]);
      }
    }
    Vjob(0); Vjob(1);
  } else {
    #pragma unroll
    for (int vt = 2; vt < 8; ++vt) Vjob(vt);
  }
  __syncthreads();
  {
    int row = t >> 2, ck = t & 3, key = (row >> 1) & 3;
    uint4 d = ((const uint4*)vbuf)[row*4 + (ck ^ key)];
    *(uint4*)(Vt8 + ((size_t)b*CC + row)*NN + nb + ck*16) = d;
  }
}

// ---- kernel 2: flash attention + fused output proj/residual. 1024 blocks x 256 thr.
// Block = (b, 32-query tile). 4 waves; per 128-key tile (32 kts): wave owns keys
// [w*32,+32) in QK and vchans [w*32,+32) in PV. K and V live in REGISTERS (L2-fed);
// only P goes through LDS (2 slots x 4KB, 128B rows, chunk16 ^ (row&7) swizzle).
// One barrier/kt: [loads][QK][softmax->P(t&1)][lgkm+bar][PV(t) w/ P+V, setprio].
__global__ __launch_bounds__(256, 4) void k_attn(const u16* Qm, const u16* Km,
                                                 const u8* Vt8, const u16* wso,
                                                 const float* x, const float* gamma,
                                                 float* out){
  __shared__ __align__(16) char smem[8704];
  // P slots @0,@4096: [32q][128k] fp8. Epilogue: Ol [32q][128c] bf16 @0; Ml [4][32] @8192.
  int bid = blockIdx.x;
  int b = bid & 7, qb = bid >> 3;      // one batch per XCD
  int t0 = threadIdx.x;
  int l = t0 & 63, a = l & 15, g = l >> 4;
  int w = t0 >> 6;
  int q0 = qb * 32;

  // Q frags (32 queries)
  bf16x8 qf[2];
  #pragma unroll
  for (int qs = 0; qs < 2; ++qs)
    qf[qs] = ((const bf16x8*)(Qm + ((size_t)b*NN + q0 + qs*16 + a) * KCQ))[g];

  // K: wave's 32-key slice, 2 subtiles, 16B/lane coalesced. V: 2 vchan rows x 4 kk, 8B/lane.
  const u16* kPtr = Km + ((size_t)b*NN + w*32 + a) * KCQ + g*8;       // += 4096 elems/kt
  const u8*  vP0  = Vt8 + ((size_t)b*CC + w*32 + a) * NN + g*8;       // += 128/kt
  const u8*  vP1  = vP0 + (size_t)16 * NN;

  f32x4 o[4];                          // [st*2+qs] = O^T[w*32+st*16+4g+r][q0+qs*16+a]
  #pragma unroll
  for (int i = 0; i < 4; ++i) o[i] = (f32x4){0.f,0.f,0.f,0.f};
  float ls[2] = {0.f, 0.f};

  const int sx = (a & 7) << 4;         // P swizzle key
  bf16x8 kfC[2];
  kfC[0] = *(const bf16x8*)(kPtr);
  kfC[1] = *(const bf16x8*)(kPtr + 512);

  for (int t = 0; t < 32; ++t){
    // V(t) frags (used by PV at phase bottom; QK+softmax+barrier cover L2 latency)
    i64 vf[8];
    #pragma unroll
    for (int kk = 0; kk < 4; ++kk){
      vf[kk]     = *(const i64*)(vP0 + t*128 + kk*32);
      vf[4 + kk] = *(const i64*)(vP1 + t*128 + kk*32);
    }
    // K(t+1) prefetch
    bf16x8 kfN[2];
    kfN[0] = *(const bf16x8*)(kPtr + (size_t)(t+1)*4096);
    kfN[1] = *(const bf16x8*)(kPtr + (size_t)(t+1)*4096 + 512);

    // QK: S^T[key w*32+su*16+4g+r][q qs*16+a]
    f32x4 sv[4];
    #pragma unroll
    for (int su = 0; su < 2; ++su)
      #pragma unroll
      for (int qs = 0; qs < 2; ++qs){
        f32x4 z = {0.f,0.f,0.f,0.f};
        sv[su*2+qs] = __builtin_amdgcn_mfma_f32_16x16x32_bf16(kfC[su], qf[qs], z, 0,0,0);
      }
    // softmax (m=0; scores bounded): p = exp2(s), fp8 pack -> P[t&1]
    char* Pw = smem + (t&1)*4096;
    #pragma unroll
    for (int su = 0; su < 2; ++su)
      #pragma unroll
      for (int qs = 0; qs < 2; ++qs){
        f32x4 s = sv[su*2+qs];
        float p0 = __builtin_amdgcn_exp2f(s[0]);
        float p1 = __builtin_amdgcn_exp2f(s[1]);
        float p2 = __builtin_amdgcn_exp2f(s[2]);
        float p3 = __builtin_amdgcn_exp2f(s[3]);
        ls[qs] += (p0 + p1) + (p2 + p3);
        *(u32*)(Pw + (qs*16 + a)*128 + (((w*2 + su) << 4) ^ sx) + 4*g) =
            pk_fp8x4(p0, p1, p2, p3);
      }
    asm volatile("s_waitcnt lgkmcnt(0)" ::: "memory");
    __builtin_amdgcn_s_barrier();

    // PV(t): O^T[w*32 slice][32 q], V from regs, P from LDS
    const char* Pr = Pw;
    __builtin_amdgcn_s_setprio(1);
    #pragma unroll
    for (int kk = 0; kk < 4; ++kk){
      int kx = (((kk*2 + (g>>1)) << 4) ^ sx) + (g&1)*8;
      i64 pf0 = *(const i64*)(Pr + a*128 + kx);
      i64 pf1 = *(const i64*)(Pr + (16 + a)*128 + kx);
      o[0] = __builtin_amdgcn_mfma_f32_16x16x32_fp8_fp8(vf[kk],   pf0, o[0], 0,0,0);
      o[1] = __builtin_amdgcn_mfma_f32_16x16x32_fp8_fp8(vf[kk],   pf1, o[1], 0,0,0);
      o[2] = __builtin_amdgcn_mfma_f32_16x16x32_fp8_fp8(vf[4+kk], pf0, o[2], 0,0,0);
      o[3] = __builtin_amdgcn_mfma_f32_16x16x32_fp8_fp8(vf[4+kk], pf1, o[3], 0,0,0);
    }
    __builtin_amdgcn_s_setprio(0);
    kfC[0] = kfN[0]; kfC[1] = kfN[1];
  }

  // ---- epilogue: l cross-wave reduce, normalize, Ol, fused Wo-GEMM + residual ----
  #pragma unroll
  for (int qs = 0; qs < 2; ++qs){
    ls[qs] += __shfl_xor(ls[qs], 16);
    ls[qs] += __shfl_xor(ls[qs], 32);
  }
  float* Ml = (float*)(smem + 8192);   // [4w][32q]
  __syncthreads();                     // PV(31) P-reads done before overlays
  if (l < 16){
    Ml[w*32 + l]      = ls[0];
    Ml[w*32 + 16 + l] = ls[1];
  }
  __syncthreads();
  u16* Ol = (u16*)smem;                // [32q][128c] bf16, chunk16 ^ (q&7)
  #pragma unroll
  for (int qs = 0; qs < 2; ++qs){
    float lsum = Ml[qs*16 + a] + Ml[32 + qs*16 + a] + Ml[64 + qs*16 + a] + Ml[96 + qs*16 + a];
    float inv = 1.f / lsum;
    #pragma unroll
    for (int st = 0; st < 2; ++st){
      f32x4 oc = o[st*2 + qs];
      uint2 pk;
      pk.x = cvtpk(oc[0]*inv, oc[1]*inv);
      pk.y = cvtpk(oc[2]*inv, oc[3]*inv);
      int chunk = (w*4 + st*2 + (g>>1)) ^ (a & 7);      // c0 = w*32+st*16+4g
      *(uint2*)((char*)Ol + (qs*16 + a)*256 + chunk*16 + (g&1)*8) = pk;
    }
  }
  __syncthreads();
  // out-GEMM: wave w -> out channels [w*32,+32), 32 q. out = x + gm * O@Wo^T
  float gm = gamma[0];
  f32x4 acc2[4];
  #pragma unroll
  for (int i = 0; i < 4; ++i) acc2[i] = (f32x4){0.f,0.f,0.f,0.f};
  #pragma unroll
  for (int kc = 0; kc < 4; ++kc){
    bf16x8 wof0 = *(const bf16x8*)(wso + (size_t)(w*32 + a)*CC + kc*32 + g*8);
    bf16x8 wof1 = *(const bf16x8*)(wso + (size_t)(w*32 + 16 + a)*CC + kc*32 + g*8);
    #pragma unroll
    for (int qs = 0; qs < 2; ++qs){
      int chunk = (kc*4 + g) ^ (a & 7);
      bf16x8 of = *(const bf16x8*)((const char*)Ol + (qs*16 + a)*256 + chunk*16);
      acc2[qs]     = __builtin_amdgcn_mfma_f32_16x16x32_bf16(wof0, of, acc2[qs],     0,0,0);
      acc2[2 + qs] = __builtin_amdgcn_mfma_f32_16x16x32_bf16(wof1, of, acc2[2 + qs], 0,0,0);
    }
  }
  #pragma unroll
  for (int st = 0; st < 2; ++st)
    #pragma unroll
    for (int qs = 0; qs < 2; ++qs)
      #pragma unroll
      for (int r = 0; r < 4; ++r){
        size_t idx = ((size_t)b*CC + w*32 + st*16 + 4*g + r)*NN + q0 + qs*16 + a;
        out[idx] = x[idx] + gm * acc2[st*2 + qs][r];
      }
}

extern "C" void kernel_launch(void* const* d_in, const int* in_sizes, int n_in,
                              void* d_out, int out_size, void* d_ws, size_t ws_size,
                              hipStream_t stream) {
  const float* x     = (const float*)d_in[0];
  const float* Wq    = (const float*)d_in[1];
  const float* Wk    = (const float*)d_in[2];
  const float* Wv    = (const float*)d_in[3];
  const float* Wo    = (const float*)d_in[4];
  const float* gamma = (const float*)d_in[5];
  float* out = (float*)d_out;

  u16* wsq = (u16*)d_ws;
  u16* wsk = wsq + 4096;
  u16* wsv = wsk + 4096;
  u16* wso = wsv + 16384;
  u16* Qm  = wso + 16384;
  u16* Km  = Qm + (size_t)BB*NN*KCQ;
  u8*  Vt8 = (u8*)(Km + (size_t)BB*NN*KCQ);

  hipLaunchKernelGGL(k_prep_w, dim3(160),  dim3(256), 0, stream, Wq, Wk, Wv, Wo, wsq, wsk, wsv, wso);
  hipLaunchKernelGGL(k_projx,  dim3(512),  dim3(512), 0, stream, x, wsq, wsk, wsv, Qm, Km, Vt8);
  hipLaunchKernelGGL(k_attn,   dim3(1024), dim3(256), 0, stream, Qm, Km, Vt8, wso, x, gamma, out);
}

// Round 10
// 82.764 us; speedup vs baseline: 1.9513x; 1.9513x over previous
//
#include <hip/hip_runtime.h>
#include <hip/hip_bf16.h>

#define BB 8
#define CC 128
#define NN 4096
#define KCQ 32

typedef unsigned short u16;
typedef unsigned int u32;
typedef unsigned char u8;
typedef __bf16 bf16x8 __attribute__((ext_vector_type(8)));
typedef float f32x4 __attribute__((ext_vector_type(4)));
typedef long i64;

typedef const __attribute__((address_space(1))) void gas_t;
typedef __attribute__((address_space(3))) void las_t;

__device__ __forceinline__ u16 f2bf(float f){
  u32 u = __builtin_bit_cast(u32, f);
  u32 r = u + 0x7FFFu + ((u >> 16) & 1u);
  return (u16)(r >> 16);
}
__device__ __forceinline__ u32 cvtpk(float lo, float hi){
  u32 r; asm("v_cvt_pk_bf16_f32 %0, %1, %2" : "=v"(r) : "v"(lo), "v"(hi)); return r;
}
__device__ __forceinline__ u32 pk_fp8x4(float a, float b, float c, float d){
  int v = 0;
  v = __builtin_amdgcn_cvt_pk_fp8_f32(a, b, v, false);
  v = __builtin_amdgcn_cvt_pk_fp8_f32(c, d, v, true);
  return (u32)v;
}
__device__ __forceinline__ void gload16(const void* g, void* l){
  __builtin_amdgcn_global_load_lds((gas_t*)g, (las_t*)l, 16, 0, 0);
}

// ---- kernel 0: weights f32 -> bf16 (Wq folds 1/sqrt(32)*log2(e) for exp2 softmax)
__global__ __launch_bounds__(256) void k_prep_w(const float* Wq, const float* Wk,
                                                const float* Wv, const float* Wo,
                                                u16* wsq, u16* wsk, u16* wsv, u16* wso){
  int i = blockIdx.x * 256 + threadIdx.x;
  const float SC = 0.2550350f; // log2(e)/sqrt(32)
  if (i < 4096)       wsq[i]        = f2bf(Wq[i] * SC);
  else if (i < 8192)  wsk[i-4096]   = f2bf(Wk[i-4096]);
  else if (i < 24576) wsv[i-8192]   = f2bf(Wv[i-8192]);
  else if (i < 40960) wso[i-24576]  = f2bf(Wo[i-24576]);
}

// ---- kernel 1: fused transpose+projection. 512 blocks x 512 thr.
__global__ __launch_bounds__(512) void k_projx(const float* x, const u16* wq, const u16* wk,
                                               const u16* wv, u16* Qm, u16* Km, u8* Vt8){
  __shared__ __align__(16) u16 xL[64*132];
  int b = blockIdx.x >> 6, nb = (blockIdx.x & 63) * 64;
  int t = threadIdx.x;
  int n = t & 63, cg = t >> 6;
  #pragma unroll
  for (int it = 0; it < 16; ++it){
    int c = it*8 + cg;
    xL[n*132 + c] = f2bf(x[((size_t)b*CC + c)*NN + nb + n]);
  }
  __syncthreads();
  int w = t >> 6, l = t & 63, a = l & 15, g = l >> 4;
  int ns = w >> 1, half = w & 1;
  int n0 = nb + ns*16;
  bf16x8 xa[4];
  #pragma unroll
  for (int kc = 0; kc < 4; ++kc)
    xa[kc] = *(const bf16x8*)(xL + (ns*16 + a)*132 + kc*32 + g*8);
  __syncthreads();

  u32* vbuf = (u32*)xL;                  // [128 vchan][16 dwords], chunk ^ ((row>>1)&3)
  auto Vjob = [&](int vt){
    f32x4 acc = {0.f,0.f,0.f,0.f};
    #pragma unroll
    for (int kc = 0; kc < 4; ++kc){
      bf16x8 wa = ((const bf16x8*)(wv + (size_t)(vt*16 + a) * CC))[kc*4 + g];
      acc = __builtin_amdgcn_mfma_f32_16x16x32_bf16(xa[kc], wa, acc, 0,0,0);
    }
    int row = vt*16 + a;
    vbuf[row*16 + ((ns ^ ((a>>1)&3)) << 2) + g] = pk_fp8x4(acc[0], acc[1], acc[2], acc[3]);
  };

  if (half == 0){
    #pragma unroll
    for (int qt = 0; qt < 2; ++qt){
      f32x4 accq = {0.f,0.f,0.f,0.f}, acck = {0.f,0.f,0.f,0.f};
      #pragma unroll
      for (int kc = 0; kc < 4; ++kc){
        bf16x8 wbq = ((const bf16x8*)(wq + (size_t)(qt*16 + a) * CC))[kc*4 + g];
        bf16x8 wbk = ((const bf16x8*)(wk + (size_t)(qt*16 + a) * CC))[kc*4 + g];
        accq = __builtin_amdgcn_mfma_f32_16x16x32_bf16(xa[kc], wbq, accq, 0,0,0);
        acck = __builtin_amdgcn_mfma_f32_16x16x32_bf16(xa[kc], wbk, acck, 0,0,0);
      }
      #pragma unroll
      for (int r = 0; r < 4; ++r){
        Qm[((size_t)b*NN + n0 + 4*g + r) * KCQ + qt*16 + a] = f2bf(accq[r]);
        Km[((size_t)b*NN + n0 + 4*g + r) * KCQ + qt*16 + a] = f2bf(acck[r]);
      }
    }
    Vjob(0); Vjob(1);
  } else {
    #pragma unroll
    for (int vt = 2; vt < 8; ++vt) Vjob(vt);
  }
  __syncthreads();
  {
    int row = t >> 2, ck = t & 3, key = (row >> 1) & 3;
    uint4 d = ((const uint4*)vbuf)[row*4 + (ck ^ key)];
    *(uint4*)(Vt8 + ((size_t)b*CC + row)*NN + nb + ck*16) = d;
  }
}

// ---- kernel 2: flash attention + fused output proj/residual. 1024 blocks x 512 thr.
// Block = (b, 32-query tile); 8 waves = 2 key-halves x 4. Wave (h,wq): keys
// [h*2048 + kt*64 + wq*16, +16) in QK; vchans [wq*32,+32) of half h in PV. K in regs,
// V LDS-dbuf (global_load_lds, staged AFTER barrier -> 2 slots race-free), P LDS-dbuf.
// One barrier/kt, vmcnt(1) keeps K-prefetch in flight. LDS 40KB -> 4 blocks/CU.
__global__ __launch_bounds__(512, 8) void k_attn(const u16* Qm, const u16* Km,
                                                 const u8* Vt8, const u16* wso,
                                                 const float* x, const float* gamma,
                                                 float* out){
  __shared__ __align__(16) char smem[40960];
  // V slot s: s*16384 + h*8192 + vchan*64   [128v][64k] fp8, chunk16 ^ ((row>>1)&3)
  // P slot s: 32768 + s*4096 + h*2048 + q*64 [32q][64k] fp8, same swizzle
  // epilogue: Cx [32q][132] f32 @0; Ol [32q][128c] bf16 @17408; Ml [8][32] f32 @32768
  int bid = blockIdx.x;
  int b = bid & 7, qb = bid >> 3;      // one batch per XCD
  int t0 = threadIdx.x;
  int l = t0 & 63, a = l & 15, g = l >> 4;
  int w = t0 >> 6, h = w >> 2, wq = w & 3;
  int q0 = qb * 32;

  // Q frags (32 queries, B-operand)
  bf16x8 qf[2];
  #pragma unroll
  for (int qs = 0; qs < 2; ++qs)
    qf[qs] = ((const bf16x8*)(Qm + ((size_t)b*NN + q0 + qs*16 + a) * KCQ))[g];

  // K running pointer (wave's 16-key slice, 16B/lane coalesced; +64 keys per kt)
  const u16* kRun = Km + ((size_t)b*NN + h*2048 + wq*16 + a) * KCQ + g*8;

  f32x4 o[4];                          // [st*2+qs] = O^T[wq*32+st*16+4g+r][q0+qs*16+a]
  #pragma unroll
  for (int i = 0; i < 4; ++i) o[i] = (f32x4){0.f,0.f,0.f,0.f};
  float ls[2] = {0.f, 0.f};

  // V staging: lane owns row wq*32+(l>>2) (+16 for 2nd gload), chunk l&3, pre-swizzled src
  int schk = (l&3) ^ ((l>>3)&3);
  const u8* vRun = Vt8 + (size_t)b*CC*NN + (size_t)(wq*32 + (l>>2))*NN + h*2048 + schk*16;
  const int vOff = h*8192 + wq*2048 + l*16;

  // prologue: stage V(0) -> slot 0; K(0) -> regs
  {
    char* vd = smem + vOff;
    gload16(vRun, vd);
    gload16(vRun + (size_t)16*NN, vd + 1024);
    vRun += 64;
  }
  bf16x8 kfC = *(const bf16x8*)kRun; kRun += 2048;

  const int cswz = (a >> 1) & 3;

  for (int t = 0; t < 32; ++t){
    bf16x8 kfN = *(const bf16x8*)kRun; kRun += 2048;

    // QK(t): S^T[key wq*16+4g+r][q qs*16+a]
    f32x4 sv[2];
    #pragma unroll
    for (int qs = 0; qs < 2; ++qs){
      f32x4 z = {0.f,0.f,0.f,0.f};
      sv[qs] = __builtin_amdgcn_mfma_f32_16x16x32_bf16(kfC, qf[qs], z, 0,0,0);
    }
    // softmax (m=0; scores bounded): p = exp2(s) -> fp8 -> P slot (t&1)
    char* Pw = smem + 32768 + (t&1)*4096 + h*2048;
    #pragma unroll
    for (int qs = 0; qs < 2; ++qs){
      float p0 = __builtin_amdgcn_exp2f(sv[qs][0]);
      float p1 = __builtin_amdgcn_exp2f(sv[qs][1]);
      float p2 = __builtin_amdgcn_exp2f(sv[qs][2]);
      float p3 = __builtin_amdgcn_exp2f(sv[qs][3]);
      ls[qs] += (p0 + p1) + (p2 + p3);
      *(u32*)(Pw + (qs*16 + a)*64 + ((wq ^ cswz) << 4) + 4*g) = pk_fp8x4(p0, p1, p2, p3);
    }
    // drain V(t) stage loads (keep kfN in flight) + P writes; sync
    if (t < 31) { asm volatile("s_waitcnt vmcnt(1) lgkmcnt(0)" ::: "memory"); }
    else        { asm volatile("s_waitcnt vmcnt(0) lgkmcnt(0)" ::: "memory"); }
    __builtin_amdgcn_s_barrier();

    // stage V(t+1) -> slot (t+1)&1 (post-barrier: all waves' PV(t-1) reads complete)
    if (t < 31){
      char* vd = smem + (((t+1)&1) << 14) + vOff;
      gload16(vRun, vd);
      gload16(vRun + (size_t)16*NN, vd + 1024);
      vRun += 64;
    }
    // PV(t): V slot (t&1), P slot (t&1)
    const char* Vs = smem + ((t&1) << 14) + h*8192;
    const char* Pr = smem + 32768 + (t&1)*4096 + h*2048;
    __builtin_amdgcn_s_setprio(1);
    #pragma unroll
    for (int kk = 0; kk < 2; ++kk){
      int kx = (((kk*2 + (g>>1)) ^ cswz) << 4) + (g&1)*8;
      i64 pf0 = *(const i64*)(Pr + a*64 + kx);
      i64 pf1 = *(const i64*)(Pr + (16 + a)*64 + kx);
      i64 vf0 = *(const i64*)(Vs + (wq*32 + a)*64 + kx);
      i64 vf1 = *(const i64*)(Vs + (wq*32 + 16 + a)*64 + kx);
      o[0] = __builtin_amdgcn_mfma_f32_16x16x32_fp8_fp8(vf0, pf0, o[0], 0,0,0);
      o[1] = __builtin_amdgcn_mfma_f32_16x16x32_fp8_fp8(vf0, pf1, o[1], 0,0,0);
      o[2] = __builtin_amdgcn_mfma_f32_16x16x32_fp8_fp8(vf1, pf0, o[2], 0,0,0);
      o[3] = __builtin_amdgcn_mfma_f32_16x16x32_fp8_fp8(vf1, pf1, o[3], 0,0,0);
    }
    __builtin_amdgcn_s_setprio(0);
    kfC = kfN;
  }

  // ---- epilogue: l reduce + publish, combine halves (m=0 -> plain sums), fused Wo-GEMM
  #pragma unroll
  for (int qs = 0; qs < 2; ++qs){
    ls[qs] += __shfl_xor(ls[qs], 16);
    ls[qs] += __shfl_xor(ls[qs], 32);
  }
  __syncthreads();                     // all PV(31) reads done -> overlays safe
  float* Ml = (float*)(smem + 32768);  // [8w][32q] (P region dead)
  if (l < 16){
    Ml[w*32 + l]      = ls[0];
    Ml[w*32 + 16 + l] = ls[1];
  }
  float* Cx = (float*)smem;            // [32q][132] f32 (V region dead)
  if (h == 1){
    #pragma unroll
    for (int st = 0; st < 2; ++st)
      #pragma unroll
      for (int qs = 0; qs < 2; ++qs)
        *(f32x4*)(Cx + (qs*16 + a)*132 + wq*32 + st*16 + 4*g) = o[st*2 + qs];
  }
  __syncthreads();
  u16* Ol = (u16*)(smem + 17408);      // [32q][128c] bf16, chunk16 ^ (q&7)
  if (h == 0){
    #pragma unroll
    for (int qs = 0; qs < 2; ++qs){
      float lsum = 0.f;
      #pragma unroll
      for (int ww = 0; ww < 8; ++ww) lsum += Ml[ww*32 + qs*16 + a];
      float inv = 1.f / lsum;
      #pragma unroll
      for (int st = 0; st < 2; ++st){
        f32x4 oc = o[st*2 + qs];
        const float* cx = Cx + (qs*16 + a)*132 + wq*32 + st*16 + 4*g;
        uint2 pk;
        pk.x = cvtpk((oc[0] + cx[0]) * inv, (oc[1] + cx[1]) * inv);
        pk.y = cvtpk((oc[2] + cx[2]) * inv, (oc[3] + cx[3]) * inv);
        int chunk = (wq*4 + st*2 + (g>>1)) ^ (a & 7);
        *(uint2*)((char*)Ol + (qs*16 + a)*256 + chunk*16 + (g&1)*8) = pk;
      }
    }
  }
  __syncthreads();
  // out-GEMM: wave w -> out channels [w*16,+16), 32 q. out = x + gm * O@Wo^T
  float gm = gamma[0];
  f32x4 acc2[2];
  acc2[0] = (f32x4){0.f,0.f,0.f,0.f};
  acc2[1] = (f32x4){0.f,0.f,0.f,0.f};
  #pragma unroll
  for (int kc = 0; kc < 4; ++kc){
    bf16x8 wof = *(const bf16x8*)(wso + (size_t)(w*16 + a)*CC + kc*32 + g*8);
    #pragma unroll
    for (int qs = 0; qs < 2; ++qs){
      int chunk = (kc*4 + g) ^ (a & 7);
      bf16x8 of = *(const bf16x8*)((const char*)Ol + (qs*16 + a)*256 + chunk*16);
      acc2[qs] = __builtin_amdgcn_mfma_f32_16x16x32_bf16(wof, of, acc2[qs], 0,0,0);
    }
  }
  #pragma unroll
  for (int qs = 0; qs < 2; ++qs)
    #pragma unroll
    for (int r = 0; r < 4; ++r){
      size_t idx = ((size_t)b*CC + w*16 + 4*g + r)*NN + q0 + qs*16 + a;
      out[idx] = x[idx] + gm * acc2[qs][r];
    }
}

extern "C" void kernel_launch(void* const* d_in, const int* in_sizes, int n_in,
                              void* d_out, int out_size, void* d_ws, size_t ws_size,
                              hipStream_t stream) {
  const float* x     = (const float*)d_in[0];
  const float* Wq    = (const float*)d_in[1];
  const float* Wk    = (const float*)d_in[2];
  const float* Wv    = (const float*)d_in[3];
  const float* Wo    = (const float*)d_in[4];
  const float* gamma = (const float*)d_in[5];
  float* out = (float*)d_out;

  u16* wsq = (u16*)d_ws;
  u16* wsk = wsq + 4096;
  u16* wsv = wsk + 4096;
  u16* wso = wsv + 16384;
  u16* Qm  = wso + 16384;
  u16* Km  = Qm + (size_t)BB*NN*KCQ;
  u8*  Vt8 = (u8*)(Km + (size_t)BB*NN*KCQ);

  hipLaunchKernelGGL(k_prep_w, dim3(160),  dim3(256), 0, stream, Wq, Wk, Wv, Wo, wsq, wsk, wsv, wso);
  hipLaunchKernelGGL(k_projx,  dim3(512),  dim3(512), 0, stream, x, wsq, wsk, wsv, Qm, Km, Vt8);
  hipLaunchKernelGGL(k_attn,   dim3(1024), dim3(512), 0, stream, Qm, Km, Vt8, wso, x, gamma, out);
}

// Round 11
// 71.423 us; speedup vs baseline: 2.2611x; 1.1588x over previous
//
#include <hip/hip_runtime.h>
#include <hip/hip_bf16.h>

#define BB 8
#define CC 128
#define NN 4096
#define KCQ 32

typedef unsigned short u16;
typedef unsigned int u32;
typedef unsigned char u8;
typedef __bf16 bf16x8 __attribute__((ext_vector_type(8)));
typedef float f32x4 __attribute__((ext_vector_type(4)));
typedef long i64;

typedef const __attribute__((address_space(1))) void gas_t;
typedef __attribute__((address_space(3))) void las_t;

__device__ __forceinline__ u16 f2bf(float f){
  u32 u = __builtin_bit_cast(u32, f);
  u32 r = u + 0x7FFFu + ((u >> 16) & 1u);
  return (u16)(r >> 16);
}
__device__ __forceinline__ u32 cvtpk(float lo, float hi){
  u32 r; asm("v_cvt_pk_bf16_f32 %0, %1, %2" : "=v"(r) : "v"(lo), "v"(hi)); return r;
}
__device__ __forceinline__ u32 pk_fp8x4(float a, float b, float c, float d){
  int v = 0;
  v = __builtin_amdgcn_cvt_pk_fp8_f32(a, b, v, false);
  v = __builtin_amdgcn_cvt_pk_fp8_f32(c, d, v, true);
  return (u32)v;
}
__device__ __forceinline__ void gload16(const void* g, void* l){
  __builtin_amdgcn_global_load_lds((gas_t*)g, (las_t*)l, 16, 0, 0);
}

// ---- kernel 0: weights f32 -> bf16 (Wq folds 1/sqrt(32)*log2(e) for exp2 softmax)
__global__ __launch_bounds__(256) void k_prep_w(const float* Wq, const float* Wk,
                                                const float* Wv, const float* Wo,
                                                u16* wsq, u16* wsk, u16* wsv, u16* wso){
  int i = blockIdx.x * 256 + threadIdx.x;
  const float SC = 0.2550350f; // log2(e)/sqrt(32)
  if (i < 4096)       wsq[i]        = f2bf(Wq[i] * SC);
  else if (i < 8192)  wsk[i-4096]   = f2bf(Wk[i-4096]);
  else if (i < 24576) wsv[i-8192]   = f2bf(Wv[i-8192]);
  else if (i < 40960) wso[i-24576]  = f2bf(Wo[i-24576]);
}

// ---- kernel 1: fused transpose+projection. 512 blocks x 512 thr.
__global__ __launch_bounds__(512) void k_projx(const float* x, const u16* wq, const u16* wk,
                                               const u16* wv, u16* Qm, u16* Km, u8* Vt8){
  __shared__ __align__(16) u16 xL[64*132];
  int b = blockIdx.x >> 6, nb = (blockIdx.x & 63) * 64;
  int t = threadIdx.x;
  int n = t & 63, cg = t >> 6;
  #pragma unroll
  for (int it = 0; it < 16; ++it){
    int c = it*8 + cg;
    xL[n*132 + c] = f2bf(x[((size_t)b*CC + c)*NN + nb + n]);
  }
  __syncthreads();
  int w = t >> 6, l = t & 63, a = l & 15, g = l >> 4;
  int ns = w >> 1, half = w & 1;
  int n0 = nb + ns*16;
  bf16x8 xa[4];
  #pragma unroll
  for (int kc = 0; kc < 4; ++kc)
    xa[kc] = *(const bf16x8*)(xL + (ns*16 + a)*132 + kc*32 + g*8);
  __syncthreads();

  u32* vbuf = (u32*)xL;                  // [128 vchan][16 dwords], chunk ^ ((row>>1)&3)
  auto Vjob = [&](int vt){
    f32x4 acc = {0.f,0.f,0.f,0.f};
    #pragma unroll
    for (int kc = 0; kc < 4; ++kc){
      bf16x8 wa = ((const bf16x8*)(wv + (size_t)(vt*16 + a) * CC))[kc*4 + g];
      acc = __builtin_amdgcn_mfma_f32_16x16x32_bf16(xa[kc], wa, acc, 0,0,0);
    }
    int row = vt*16 + a;
    vbuf[row*16 + ((ns ^ ((a>>1)&3)) << 2) + g] = pk_fp8x4(acc[0], acc[1], acc[2], acc[3]);
  };

  if (half == 0){
    #pragma unroll
    for (int qt = 0; qt < 2; ++qt){
      f32x4 accq = {0.f,0.f,0.f,0.f}, acck = {0.f,0.f,0.f,0.f};
      #pragma unroll
      for (int kc = 0; kc < 4; ++kc){
        bf16x8 wbq = ((const bf16x8*)(wq + (size_t)(qt*16 + a) * CC))[kc*4 + g];
        bf16x8 wbk = ((const bf16x8*)(wk + (size_t)(qt*16 + a) * CC))[kc*4 + g];
        accq = __builtin_amdgcn_mfma_f32_16x16x32_bf16(xa[kc], wbq, accq, 0,0,0);
        acck = __builtin_amdgcn_mfma_f32_16x16x32_bf16(xa[kc], wbk, acck, 0,0,0);
      }
      #pragma unroll
      for (int r = 0; r < 4; ++r){
        Qm[((size_t)b*NN + n0 + 4*g + r) * KCQ + qt*16 + a] = f2bf(accq[r]);
        Km[((size_t)b*NN + n0 + 4*g + r) * KCQ + qt*16 + a] = f2bf(acck[r]);
      }
    }
    Vjob(0); Vjob(1);
  } else {
    #pragma unroll
    for (int vt = 2; vt < 8; ++vt) Vjob(vt);
  }
  __syncthreads();
  {
    int row = t >> 2, ck = t & 3, key = (row >> 1) & 3;
    uint4 d = ((const uint4*)vbuf)[row*4 + (ck ^ key)];
    *(uint4*)(Vt8 + ((size_t)b*CC + row)*NN + nb + ck*16) = d;
  }
}

// ---- kernel 2: flash attention + fused output proj/residual. 512 blocks x 512 thr.
// R8 structure (q-tile 64, 2 key-halves x 4 waves, V 3-slot LDS, P 2-slot, 1 bar/kt)
// with intra-wave pipeline: per kt after barrier: QK(t+1) [regs] -> PV(t) [MFMA] ->
// softmax(t+1) [VALU overlaps PV] -> stage V(t+2)+prefetch K(t+2) -> vmcnt(3)+bar.
__global__ __launch_bounds__(512, 4) void k_attn(const u16* Qm, const u16* Km,
                                                 const u8* Vt8, const u16* wso,
                                                 const float* x, const float* gamma,
                                                 float* out){
  __shared__ __align__(16) char smem[65536];
  // V slot s(0..2): s*16384 + h*8192 + vchan*64  [128][64B] fp8, chunk-XOR ((row>>1)&3)
  // P slot p(0..1): 49152 + p*8192 + h*4096 + q*64 [64][64B] fp8, same swizzle
  // epilogue overlays: Cx [64][132] f32 @0; Ml [8][64] f32 @36864; Ol [64][128] bf16 @49152
  int bid = blockIdx.x;
  int b = bid & 7, qb = bid >> 3;      // one batch per XCD
  int t0 = threadIdx.x;
  int l = t0 & 63, a = l & 15, g = l >> 4;
  int w = t0 >> 6, h = w >> 2, wq = w & 3;
  int q0 = qb * 64;
  int kb0 = h * 2048;

  const u8* Vb = Vt8 + (size_t)b * CC * NN;

  bf16x8 qf[4];
  #pragma unroll
  for (int qs = 0; qs < 4; ++qs)
    qf[qs] = ((const bf16x8*)(Qm + ((size_t)b*NN + q0 + qs*16 + a) * KCQ))[g];
  const u16* kPtr = Km + ((size_t)b*NN + kb0 + wq*16 + a) * KCQ + g*8;

  f32x4 o[8];                          // [qs*2+st] = O^T[wq*32+st*16+4g+r][qs*16+a]
  #pragma unroll
  for (int i = 0; i < 8; ++i) o[i] = (f32x4){0.f,0.f,0.f,0.f};
  float ls[4] = {0.f, 0.f, 0.f, 0.f};

  int schk = (l&3) ^ ((l>>3)&3);
  const u8* vSrc = Vb + (size_t)(wq*32 + (l>>2))*NN + kb0 + (schk << 4);
  const int vOff = h*8192 + wq*2048 + l*16;
  auto stageV = [&](int t1, int sl){
    const u8* vs = vSrc + t1*64;
    char* vd = smem + sl*16384 + vOff;
    gload16(vs, vd);
    gload16(vs + (size_t)16*NN, vd + 1024);
  };

  const int cswz = (a >> 1) & 3;
  auto PV = [&](int ps, int vsl){
    const char* Vs = smem + vsl*16384 + h*8192;
    const char* Pr = smem + 49152 + ps*8192 + h*4096;
    __builtin_amdgcn_s_setprio(1);
    #pragma unroll
    for (int kk = 0; kk < 2; ++kk){
      int kx = (((kk*2 + (g>>1)) ^ cswz) << 4) + (g&1)*8;
      i64 vf0 = *(const i64*)(Vs + (wq*32 + a)*64 + kx);
      i64 vf1 = *(const i64*)(Vs + (wq*32 + 16 + a)*64 + kx);
      i64 pf[4];
      #pragma unroll
      for (int qs = 0; qs < 4; ++qs)
        pf[qs] = *(const i64*)(Pr + (qs*16 + a)*64 + kx);
      #pragma unroll
      for (int qs = 0; qs < 4; ++qs){
        o[qs*2  ] = __builtin_amdgcn_mfma_f32_16x16x32_fp8_fp8(vf0, pf[qs], o[qs*2  ], 0,0,0);
        o[qs*2+1] = __builtin_amdgcn_mfma_f32_16x16x32_fp8_fp8(vf1, pf[qs], o[qs*2+1], 0,0,0);
      }
    }
    __builtin_amdgcn_s_setprio(0);
  };

  auto SM = [&](const f32x4* sv, char* Pw){
    #pragma unroll
    for (int qs = 0; qs < 4; ++qs){
      float p0 = __builtin_amdgcn_exp2f(sv[qs][0]);
      float p1 = __builtin_amdgcn_exp2f(sv[qs][1]);
      float p2 = __builtin_amdgcn_exp2f(sv[qs][2]);
      float p3 = __builtin_amdgcn_exp2f(sv[qs][3]);
      ls[qs] += (p0 + p1) + (p2 + p3);
      *(u32*)(Pw + (qs*16 + a)*64 + ((wq ^ cswz) << 4) + 4*g) = pk_fp8x4(p0, p1, p2, p3);
    }
  };

  char* PwBase = smem + 49152 + h*4096;

  // prologue: K(0),K(1) loads FIRST (so QK(0)'s implicit wait drains nothing else),
  // then V(0),V(1) stages; QK(0); SM(0)->P slot0; vmcnt(2)=leave V(1); bar.
  bf16x8 kfC = *(const bf16x8*)(kPtr);               // K(0)
  bf16x8 kfN = *(const bf16x8*)(kPtr + 2048);        // K(1)
  stageV(0, 0);
  stageV(1, 1);
  {
    f32x4 sv[4];
    #pragma unroll
    for (int qs = 0; qs < 4; ++qs){
      f32x4 z = {0.f,0.f,0.f,0.f};
      sv[qs] = __builtin_amdgcn_mfma_f32_16x16x32_bf16(kfC, qf[qs], z, 0,0,0);
    }
    SM(sv, PwBase);                                  // P slot 0
  }
  asm volatile("s_waitcnt vmcnt(2) lgkmcnt(0)" ::: "memory");
  __builtin_amdgcn_s_barrier();

  int vR = 0;                          // V slot of tile t (t%3)
  for (int t = 0; t < 31; ++t){
    // QK(t+1): register-only inputs
    f32x4 sv[4];
    #pragma unroll
    for (int qs = 0; qs < 4; ++qs){
      f32x4 z = {0.f,0.f,0.f,0.f};
      sv[qs] = __builtin_amdgcn_mfma_f32_16x16x32_bf16(kfN, qf[qs], z, 0,0,0);
    }
    // PV(t): P slot t&1, V slot t%3 — overlaps softmax below on MFMA pipe
    PV(t & 1, vR);
    // softmax(t+1) -> P slot (t+1)&1 (readers of (t-1)&1 drained before last bar)
    SM(sv, PwBase + ((t+1)&1)*8192);
    // stage V(t+2), prefetch K(t+2)
    if (t < 30){
      kfC = *(const bf16x8*)(kPtr + (size_t)(t+2)*2048);
      int sl = vR >= 1 ? vR - 1 : 2;   // (t+2)%3
      stageV(t+2, sl);
      asm volatile("s_waitcnt vmcnt(3) lgkmcnt(0)" ::: "memory");  // V(t+1)+older landed
    } else {
      asm volatile("s_waitcnt vmcnt(0) lgkmcnt(0)" ::: "memory");
    }
    __builtin_amdgcn_s_barrier();
    kfN = kfC;
    vR = (vR == 2) ? 0 : vR + 1;
  }
  PV(1, vR);                           // tail: PV(31), P slot 1, V slot 31%3=1

  // ---- fused epilogue (R8) ----
  #pragma unroll
  for (int qs = 0; qs < 4; ++qs){
    ls[qs] += __shfl_xor(ls[qs], 16);
    ls[qs] += __shfl_xor(ls[qs], 32);
  }
  float* Ml = (float*)(smem + 36864);   // V slot 2 region (dead: V(29) drained)
  if (l < 16){
    #pragma unroll
    for (int qs = 0; qs < 4; ++qs) Ml[w*64 + qs*16 + l] = ls[qs];
  }
  float* Cx = (float*)smem;             // V slots 0-1 (dead after X1)
  __syncthreads();                      // X1
  if (h == 1){
    #pragma unroll
    for (int i = 0; i < 8; ++i){
      int qs = i >> 1, st = i & 1;
      *(f32x4*)(Cx + (qs*16 + a)*132 + wq*32 + st*16 + 4*g) = o[i];
    }
  }
  __syncthreads();                      // X2
  u16* Ol = (u16*)(smem + 49152);       // [64q][128c] bf16, chunk16 ^ (q&7)
  if (h == 0){
    #pragma unroll
    for (int qs = 0; qs < 4; ++qs){
      float lsum = 0.f;
      #pragma unroll
      for (int ww = 0; ww < 8; ++ww) lsum += Ml[ww*64 + qs*16 + a];
      float inv = 1.f / lsum;
      #pragma unroll
      for (int st = 0; st < 2; ++st){
        f32x4 oc = o[qs*2 + st];
        const float* cx = Cx + (qs*16 + a)*132 + wq*32 + st*16 + 4*g;
        uint2 pk;
        pk.x = cvtpk((oc[0] + cx[0]) * inv, (oc[1] + cx[1]) * inv);
        pk.y = cvtpk((oc[2] + cx[2]) * inv, (oc[3] + cx[3]) * inv);
        int chunk = (wq*4 + st*2 + (g>>1)) ^ (a & 7);   // c0 = wq*32+st*16+4g
        *(uint2*)((char*)Ol + (qs*16 + a)*256 + chunk*16 + (g&1)*8) = pk;
      }
    }
  }
  __syncthreads();                      // X3
  // out-GEMM: wave w -> out rows [w*16,+16), all 64 q. out = x + gm * O@Wo^T
  float gm = gamma[0];
  f32x4 acc2[4];
  #pragma unroll
  for (int qs = 0; qs < 4; ++qs) acc2[qs] = (f32x4){0.f,0.f,0.f,0.f};
  #pragma unroll
  for (int kc = 0; kc < 4; ++kc){
    bf16x8 wof = *(const bf16x8*)(wso + (size_t)(w*16 + a)*CC + kc*32 + g*8);
    #pragma unroll
    for (int qs = 0; qs < 4; ++qs){
      int chunk = (kc*4 + g) ^ (a & 7);
      bf16x8 of = *(const bf16x8*)((const char*)Ol + (qs*16 + a)*256 + chunk*16);
      acc2[qs] = __builtin_amdgcn_mfma_f32_16x16x32_bf16(wof, of, acc2[qs], 0,0,0);
    }
  }
  #pragma unroll
  for (int qs = 0; qs < 4; ++qs){
    #pragma unroll
    for (int r = 0; r < 4; ++r){
      size_t idx = ((size_t)b*CC + w*16 + 4*g + r)*NN + q0 + qs*16 + a;
      out[idx] = x[idx] + gm * acc2[qs][r];
    }
  }
}

extern "C" void kernel_launch(void* const* d_in, const int* in_sizes, int n_in,
                              void* d_out, int out_size, void* d_ws, size_t ws_size,
                              hipStream_t stream) {
  const float* x     = (const float*)d_in[0];
  const float* Wq    = (const float*)d_in[1];
  const float* Wk    = (const float*)d_in[2];
  const float* Wv    = (const float*)d_in[3];
  const float* Wo    = (const float*)d_in[4];
  const float* gamma = (const float*)d_in[5];
  float* out = (float*)d_out;

  u16* wsq = (u16*)d_ws;
  u16* wsk = wsq + 4096;
  u16* wsv = wsk + 4096;
  u16* wso = wsv + 16384;
  u16* Qm  = wso + 16384;
  u16* Km  = Qm + (size_t)BB*NN*KCQ;
  u8*  Vt8 = (u8*)(Km + (size_t)BB*NN*KCQ);

  hipLaunchKernelGGL(k_prep_w, dim3(160), dim3(256), 0, stream, Wq, Wk, Wv, Wo, wsq, wsk, wsv, wso);
  hipLaunchKernelGGL(k_projx,  dim3(512), dim3(512), 0, stream, x, wsq, wsk, wsv, Qm, Km, Vt8);
  hipLaunchKernelGGL(k_attn,   dim3(512), dim3(512), 0, stream, Qm, Km, Vt8, wso, x, gamma, out);
}